// Round 5
// baseline (228.047 us; speedup 1.0000x reference)
//
#include <hip/hip_runtime.h>

// FocalCTCLoss on MI355X — round 10: barrier-free, LDS-free main loop.
// B=256, T=1024, V=128 (BLANK=127), L=64, S=129.
//
// Round-9 post-mortem: scratch eliminated (WRITE 16.7MB->8KB) and fused
// dropped 198->80 us, total tracking fused 1:1. But 80 us = ~187 cy/DP-step
// vs ~25 modeled; both the 9-barrier (round5) and 36-barrier (round9)
// phase structures land at 150-220 cy/step. The phase/barrier coupling is
// the un-modeled cost. This round deletes it:
//  - wave 0 (consumer): DP reads u[t][lab] and u[t][127] DIRECTLY from
//    global (L1/L2), 16-step rotation of named regs = 32 outstanding
//    loads. Worst-case all-miss throughput 900/16 ~= 56 cy/step = 24 us.
//  - waves 1..15 (streamers): independent coalesced float4 row streaming
//    (1 KB/instr), per-row log2 denominators in registers; they double as
//    the consumer's L2 prefetcher (same scan direction, ~same front).
//  - NO barriers, NO LDS tile, NO gather waves. One __syncthreads before
//    the final 30-entry reduce.
// Numerics identical to round 9 (passed): rescale check every 16 steps at
// 2^-75, same recursion, same denominator factorization.

#define EPSF 1e-7f

constexpr int Bb = 256;
constexpr int Tt = 1024;
constexpr int Vv = 128;
constexpr int Ll = 64;

// ---- DPP helpers -----------------------------------------------------------
template <int Ctrl, int RowMask, int BankMask, bool BoundCtrl>
__device__ __forceinline__ float dppf(float x) {
    return __int_as_float(__builtin_amdgcn_update_dpp(
        0, __float_as_int(x), Ctrl, RowMask, BankMask, BoundCtrl));
}

// Wave-64 sum, valid on lane 63 (inputs >= 0; 0-fill is identity).
__device__ __forceinline__ float wave_sum63(float x) {
    x += dppf<0x111, 0xf, 0xf, true>(x);
    x += dppf<0x112, 0xf, 0xf, true>(x);
    x += dppf<0x114, 0xf, 0xf, true>(x);
    x += dppf<0x118, 0xf, 0xf, true>(x);
    x += dppf<0x142, 0xa, 0xf, false>(x);  // row_bcast15 -> rows 1,3
    x += dppf<0x143, 0xc, 0xf, false>(x);  // row_bcast31 -> rows 2,3
    return x;
}

// Half-wave sums: lane 31 = sum(lanes 0..31), lane 63 = sum(lanes 32..63).
__device__ __forceinline__ float half_sum(float x) {
    x += dppf<0x111, 0xf, 0xf, true>(x);
    x += dppf<0x112, 0xf, 0xf, true>(x);
    x += dppf<0x114, 0xf, 0xf, true>(x);
    x += dppf<0x118, 0xf, 0xf, true>(x);
    x += dppf<0x142, 0xa, 0xf, false>(x);
    return x;
}

// Wave-64 max (non-negative inputs), valid on lane 63.
__device__ __forceinline__ float wave_max63(float x) {
    x = fmaxf(x, dppf<0x111, 0xf, 0xf, true>(x));
    x = fmaxf(x, dppf<0x112, 0xf, 0xf, true>(x));
    x = fmaxf(x, dppf<0x114, 0xf, 0xf, true>(x));
    x = fmaxf(x, dppf<0x118, 0xf, 0xf, true>(x));
    x = fmaxf(x, dppf<0x142, 0xa, 0xf, false>(x));
    x = fmaxf(x, dppf<0x143, 0xc, 0xf, false>(x));
    return x;
}

__device__ __forceinline__ float bcast63(float x) {
    return __int_as_float(__builtin_amdgcn_readlane(__float_as_int(x), 63));
}

// ---- DP step (textual; updates a_even/a_odd/a128/eacc in enclosing scope) --
#define DO_STEP(QE, QB, CHK)                                                 \
    do {                                                                     \
        const float am1_ = dppf<0x138, 0xf, 0xf, true>(a_odd);               \
        const float ne_  = (a_even + am1_) * (QB);                           \
        const float no_  = fmaf(maskf, am1_, a_odd + a_even) * (QE);         \
        const float n1_  = (a128 + a_odd) * (QB);                            \
        a_even = ne_; a_odd = no_; a128 = n1_;                               \
        if (CHK) {                                                           \
            const float m_ = fmaxf(fmaxf(a_even, a_odd), a128);              \
            if (__all(m_ < 0x1p-75f)) {                                      \
                const float    wmax_  = bcast63(wave_max63(m_));             \
                const unsigned e_     = __float_as_uint(wmax_) >> 23;        \
                const float    scale_ = __uint_as_float((254u - e_) << 23);  \
                eacc += (int)e_ - 127;                                       \
                a_even *= scale_; a_odd *= scale_; a128 *= scale_;           \
            }                                                                \
        }                                                                    \
    } while (0)

// ---- consumer sub-step: use (GQ,BQ) for step t0+J, reload for t0+16+J ------
#define CSTEP(J, GQ, BQ, CHK)                                                \
    do {                                                                     \
        const float qe_ = GQ + EPSF, qb_ = BQ + EPSF;                        \
        const int   tn_ = t0 + 16 + (J);                                     \
        GQ = ygl[tn_ * Vv + lab];                                            \
        BQ = ygl[tn_ * Vv + (Vv - 1)];                                       \
        DO_STEP(qe_, qb_, CHK);                                              \
    } while (0)

// ---- fused kernel: one block per batch element -----------------------------
__launch_bounds__(1024, 1)
__global__ void fused_kernel(const int* __restrict__ y_true,
                             const float* __restrict__ y_pred,
                             float* __restrict__ focal_ws) {
    const int b    = blockIdx.x;
    const int lane = threadIdx.x & 63;
    const int wv   = threadIdx.x >> 6;  // 0..15

    const float*  ygl = y_pred + (size_t)b * Tt * Vv;
    const float4* yb4 = (const float4*)ygl;

    __shared__ float part[30];  // streamer half-wave denominator partials

    if (wv >= 1) {
        // ---- streamer: rows hw2, hw2+30, ... (full wave covers 2 rows/ld) --
        const int hw2 = 2 * (wv - 1) + (lane >> 5);  // 0..29
        const int c32 = lane & 31;
        float ll = 0.0f;
#pragma unroll 5
        for (int k = 0; k < 35; ++k) {
            const int r  = hw2 + 30 * k;
            const int rc = (r < Tt) ? r : (Tt - 1);
            const float4 v = yb4[rc * (Vv / 4) + c32];
            const float  s = half_sum(v.x + v.y + v.z + v.w);
            if (r < Tt && c32 == 31)
                ll += __log2f(s + (float)Vv * EPSF);
        }
        if (c32 == 31) part[hw2] = ll;
    } else {
        // ---- consumer: serial CTC alpha recursion, global-direct reads -----
        const int lab = y_true[b * Ll + lane];  // label of odd state 2*lane+1
        const int labp = __shfl_up(lab, 1);
        const float maskf = (lane == 0 || lab != labp) ? 1.0f : 0.0f;
        float a_even = (lane == 0) ? 1.0f : 0.0f;  // pre-t0 init
        float a_odd = 0.0f, a128 = 0.0f;
        int   eacc = 0;

        __builtin_amdgcn_s_setprio(1);
        // 16-deep prefetch in NAMED registers (32 outstanding vmem loads).
        float gq0  = ygl[0 * Vv + lab],  bq0  = ygl[0 * Vv + Vv - 1];
        float gq1  = ygl[1 * Vv + lab],  bq1  = ygl[1 * Vv + Vv - 1];
        float gq2  = ygl[2 * Vv + lab],  bq2  = ygl[2 * Vv + Vv - 1];
        float gq3  = ygl[3 * Vv + lab],  bq3  = ygl[3 * Vv + Vv - 1];
        float gq4  = ygl[4 * Vv + lab],  bq4  = ygl[4 * Vv + Vv - 1];
        float gq5  = ygl[5 * Vv + lab],  bq5  = ygl[5 * Vv + Vv - 1];
        float gq6  = ygl[6 * Vv + lab],  bq6  = ygl[6 * Vv + Vv - 1];
        float gq7  = ygl[7 * Vv + lab],  bq7  = ygl[7 * Vv + Vv - 1];
        float gq8  = ygl[8 * Vv + lab],  bq8  = ygl[8 * Vv + Vv - 1];
        float gq9  = ygl[9 * Vv + lab],  bq9  = ygl[9 * Vv + Vv - 1];
        float gq10 = ygl[10 * Vv + lab], bq10 = ygl[10 * Vv + Vv - 1];
        float gq11 = ygl[11 * Vv + lab], bq11 = ygl[11 * Vv + Vv - 1];
        float gq12 = ygl[12 * Vv + lab], bq12 = ygl[12 * Vv + Vv - 1];
        float gq13 = ygl[13 * Vv + lab], bq13 = ygl[13 * Vv + Vv - 1];
        float gq14 = ygl[14 * Vv + lab], bq14 = ygl[14 * Vv + Vv - 1];
        float gq15 = ygl[15 * Vv + lab], bq15 = ygl[15 * Vv + Vv - 1];

        // main: t = 0..1007 (63 iters x 16); reloads cover t = 16..1023.
        for (int t0 = 0; t0 < Tt - 16; t0 += 16) {
            CSTEP(0,  gq0,  bq0,  false);
            CSTEP(1,  gq1,  bq1,  false);
            CSTEP(2,  gq2,  bq2,  false);
            CSTEP(3,  gq3,  bq3,  false);
            CSTEP(4,  gq4,  bq4,  false);
            CSTEP(5,  gq5,  bq5,  false);
            CSTEP(6,  gq6,  bq6,  false);
            CSTEP(7,  gq7,  bq7,  false);
            CSTEP(8,  gq8,  bq8,  false);
            CSTEP(9,  gq9,  bq9,  false);
            CSTEP(10, gq10, bq10, false);
            CSTEP(11, gq11, bq11, false);
            CSTEP(12, gq12, bq12, false);
            CSTEP(13, gq13, bq13, false);
            CSTEP(14, gq14, bq14, false);
            CSTEP(15, gq15, bq15, true);   // checks at t % 16 == 15
        }
        // tail: t = 1008..1023 (no reload); check at t = 1023.
        DO_STEP(gq0 + EPSF,  bq0 + EPSF,  false);
        DO_STEP(gq1 + EPSF,  bq1 + EPSF,  false);
        DO_STEP(gq2 + EPSF,  bq2 + EPSF,  false);
        DO_STEP(gq3 + EPSF,  bq3 + EPSF,  false);
        DO_STEP(gq4 + EPSF,  bq4 + EPSF,  false);
        DO_STEP(gq5 + EPSF,  bq5 + EPSF,  false);
        DO_STEP(gq6 + EPSF,  bq6 + EPSF,  false);
        DO_STEP(gq7 + EPSF,  bq7 + EPSF,  false);
        DO_STEP(gq8 + EPSF,  bq8 + EPSF,  false);
        DO_STEP(gq9 + EPSF,  bq9 + EPSF,  false);
        DO_STEP(gq10 + EPSF, bq10 + EPSF, false);
        DO_STEP(gq11 + EPSF, bq11 + EPSF, false);
        DO_STEP(gq12 + EPSF, bq12 + EPSF, false);
        DO_STEP(gq13 + EPSF, bq13 + EPSF, false);
        DO_STEP(gq14 + EPSF, bq14 + EPSF, false);
        DO_STEP(gq15 + EPSF, bq15 + EPSF, true);
        __builtin_amdgcn_s_setprio(0);

        __syncthreads();  // consumer side of the single block-wide sync

        // ---- final combine (wave 0) ---------------------------------------
        float vs = (lane < 30) ? part[lane] : 0.0f;
        vs = wave_sum63(vs);
        if (lane == 63) {
            const float acc_ld  = vs;  // sum_t log2(S_t + V*eps)
            const float tot     = fmaxf(a128 + a_odd, 1e-37f);
            const float log2lik = __log2f(tot) + (float)eacc - acc_ld;
            const float ln_lik  = 0.69314718055994530942f * log2lik;
            const float loss    = -ln_lik;
            const float pp      = __expf(ln_lik);
            const float om      = 1.0f - pp;
            focal_ws[b] = 0.25f * om * om * loss;
        }
        return;
    }
    __syncthreads();  // streamer side of the single block-wide sync
}

// ---- focal mean -------------------------------------------------------------
__global__ void finalize_kernel(const float* __restrict__ focal_ws,
                                float* __restrict__ out) {
    const int i    = threadIdx.x;  // 256 threads = 4 waves
    const int lane = i & 63;
    const int wv   = i >> 6;

    float f = focal_ws[i];
#pragma unroll
    for (int off = 32; off > 0; off >>= 1) f += __shfl_xor(f, off);

    __shared__ float red[4];
    if (lane == 0) red[wv] = f;
    __syncthreads();
    if (i == 0)
        out[0] = (red[0] + red[1] + red[2] + red[3]) * (1.0f / (float)Bb);
}

extern "C" void kernel_launch(void* const* d_in, const int* in_sizes, int n_in,
                              void* d_out, int out_size, void* d_ws, size_t ws_size,
                              hipStream_t stream) {
    const int*   y_true = (const int*)d_in[0];    // [B, L] int32
    const float* y_pred = (const float*)d_in[1];  // [B, T, V] float32
    float* focal_ws = (float*)d_ws;               // [B]

    fused_kernel<<<Bb, 1024, 0, stream>>>(y_true, y_pred, focal_ws);
    finalize_kernel<<<1, 256, 0, stream>>>(focal_ws, (float*)d_out);
}

// Round 8
// 198.519 us; speedup vs baseline: 1.1487x; 1.1487x over previous
//
#include <hip/hip_runtime.h>

// FocalCTCLoss on MI355X — round 13: transposed-float4 consumer (x4 latency
// amortization), plain HIP only. B=256, T=1024, V=128 (BLANK=127), L=64.
//
// r11/r12 post-mortem: two inline-asm counted-vmcnt pipelines failed (core
// dump; absmax=inf from garbage rotation registers). Mechanism abandoned.
// r10's measured fact stands: the serial chain pays ~full load latency PER
// STEP because the compiler sinks any prefetch rotation to depth ~1.
//
// This round amortizes latency algebraically: one ds_read_b128 covers 4 DP
// steps. Gather waves build gT[tblk][lane] = float4(u[4t..4t+3][lab_lane])
// (transposed, blocked, double-buffered; 33 KB LDS) reading straight from
// global (L2-warm behind the streamers). Streamers no longer touch LDS.
// Consumer: 16 float4-pairs per chunk, 2-deep named rotation, static
// indices, __syncthreads phases — the r5/r9/r10-proven sync path, zero asm.
// Even fully sunk (depth-1) this is ~45 cy/step vs r10's 215.
// Numerics bit-identical to r10 (passed).

#define EPSF 1e-7f

constexpr int Bb  = 256;
constexpr int Tt  = 1024;
constexpr int Vv  = 128;
constexpr int Ll  = 64;
constexpr int CH  = 64;          // timesteps per chunk
constexpr int NCH = Tt / CH;     // 16 chunks
constexpr int NPH = NCH + 1;     // 17 phases (gather p / consume p-1)
constexpr int NSH = 26;          // streamer half-waves (wv 3..15)

// ---- DPP helpers -----------------------------------------------------------
template <int Ctrl, int RowMask, int BankMask, bool BoundCtrl>
__device__ __forceinline__ float dppf(float x) {
    return __int_as_float(__builtin_amdgcn_update_dpp(
        0, __float_as_int(x), Ctrl, RowMask, BankMask, BoundCtrl));
}

// Wave-64 sum, valid on lane 63 (inputs >= 0; 0-fill is identity).
__device__ __forceinline__ float wave_sum63(float x) {
    x += dppf<0x111, 0xf, 0xf, true>(x);
    x += dppf<0x112, 0xf, 0xf, true>(x);
    x += dppf<0x114, 0xf, 0xf, true>(x);
    x += dppf<0x118, 0xf, 0xf, true>(x);
    x += dppf<0x142, 0xa, 0xf, false>(x);  // row_bcast15 -> rows 1,3
    x += dppf<0x143, 0xc, 0xf, false>(x);  // row_bcast31 -> rows 2,3
    return x;
}

// Half-wave sums: lane 31 = sum(lanes 0..31), lane 63 = sum(lanes 32..63).
__device__ __forceinline__ float half_sum(float x) {
    x += dppf<0x111, 0xf, 0xf, true>(x);
    x += dppf<0x112, 0xf, 0xf, true>(x);
    x += dppf<0x114, 0xf, 0xf, true>(x);
    x += dppf<0x118, 0xf, 0xf, true>(x);
    x += dppf<0x142, 0xa, 0xf, false>(x);
    return x;
}

// Wave-64 max (non-negative inputs), valid on lane 63.
__device__ __forceinline__ float wave_max63(float x) {
    x = fmaxf(x, dppf<0x111, 0xf, 0xf, true>(x));
    x = fmaxf(x, dppf<0x112, 0xf, 0xf, true>(x));
    x = fmaxf(x, dppf<0x114, 0xf, 0xf, true>(x));
    x = fmaxf(x, dppf<0x118, 0xf, 0xf, true>(x));
    x = fmaxf(x, dppf<0x142, 0xa, 0xf, false>(x));
    x = fmaxf(x, dppf<0x143, 0xc, 0xf, false>(x));
    return x;
}

__device__ __forceinline__ float bcast63(float x) {
    return __int_as_float(__builtin_amdgcn_readlane(__float_as_int(x), 63));
}

// ---- DP step (textual; updates a_even/a_odd/a128/eacc in enclosing scope) --
#define DO_STEP(QE, QB, CHK)                                                 \
    do {                                                                     \
        const float am1_ = dppf<0x138, 0xf, 0xf, true>(a_odd);               \
        const float ne_  = (a_even + am1_) * (QB);                           \
        const float no_  = fmaf(maskf, am1_, a_odd + a_even) * (QE);         \
        const float n1_  = (a128 + a_odd) * (QB);                            \
        a_even = ne_; a_odd = no_; a128 = n1_;                               \
        if (CHK) {                                                           \
            const float m_ = fmaxf(fmaxf(a_even, a_odd), a128);              \
            if (__all(m_ < 0x1p-75f)) {                                      \
                const float    wmax_  = bcast63(wave_max63(m_));             \
                const unsigned e_     = __float_as_uint(wmax_) >> 23;        \
                const float    scale_ = __uint_as_float((254u - e_) << 23);  \
                eacc += (int)e_ - 127;                                       \
                a_even *= scale_; a_odd *= scale_; a128 *= scale_;           \
            }                                                                \
        }                                                                    \
    } while (0)

// ---- fused kernel: one block per batch element -----------------------------
__launch_bounds__(1024, 1)
__global__ void fused_kernel(const int* __restrict__ y_true,
                             const float* __restrict__ y_pred,
                             float* __restrict__ focal_ws) {
    const int b    = blockIdx.x;
    const int lane = threadIdx.x & 63;
    const int wv   = threadIdx.x >> 6;  // 0..15

    const float*  ygl = y_pred + (size_t)b * Tt * Vv;
    const float4* yb4 = (const float4*)ygl;

    // gT blocked: per chunk, [CH/4 tblk][64 lane] float4 = 16 KB; x2 buffers.
    __shared__ float4 gt4[2 * (CH / 4) * 64];  // 32 KB
    __shared__ float4 bk4[2 * (CH / 4)];       // 512 B (blank, t-major f4)
    __shared__ float  part[NSH];               // denominator partials

    // ---- per-role registers ------------------------------------------------
    int lab = 0;
    if (wv <= 2) lab = y_true[b * Ll + lane];  // label of odd state 2*lane+1

    // consumer state (wave 0; meaningful on lane 63)
    float a_even = 0.0f, a_odd = 0.0f, a128 = 0.0f, maskf = 0.0f;
    int   eacc = 0;
    if (wv == 0) {
        const int labp = __shfl_up(lab, 1);
        maskf  = (lane == 0 || lab != labp) ? 1.0f : 0.0f;
        a_even = (lane == 0) ? 1.0f : 0.0f;  // pre-t0 init
    }

    // streamer identity (wv 3..15)
    const int h   = 2 * (wv - 3) + (lane >> 5);  // half-wave id 0..25
    const int c32 = lane & 31;
    float ll = 0.0f;  // lanes 31/63: sum of log2 row-sums

    // ---- 17 phases: gather(p) || consume(p-1) || stream(p); barrier --------
    for (int p = 0; p < NPH; ++p) {
        if (wv >= 3) {
            // ---- streamer: denominator row-sums for chunk p ----------------
            if (p < NCH) {
                const float4* src4 = yb4 + p * CH * (Vv / 4);
                const float4 v0 = src4[h * 32 + c32];
                const float4 v1 = src4[(h + 26) * 32 + c32];
                const float  s0 = half_sum(v0.x + v0.y + v0.z + v0.w);
                const float  s1 = half_sum(v1.x + v1.y + v1.z + v1.w);
                if (c32 == 31)
                    ll += __log2f(s0 + (float)Vv * EPSF) +
                          __log2f(s1 + (float)Vv * EPSF);
                if (h < 12) {
                    const float4 v2 = src4[(h + 52) * 32 + c32];
                    const float  s2 = half_sum(v2.x + v2.y + v2.z + v2.w);
                    if (c32 == 31) ll += __log2f(s2 + (float)Vv * EPSF);
                }
            } else if (c32 == 31) {
                part[h] = ll;  // publish at p == NCH
            }
        } else if (wv >= 1) {
            // ---- gather: chunk p -> transposed blocked LDS -----------------
            if (p < NCH) {
                const int    tg0 = (wv - 1) * 32;  // wv1: 0..31, wv2: 32..63
                const float* src = ygl + p * CH * Vv;
                float* gtw = (float*)(gt4 + (p & 1) * (CH / 4) * 64);
#pragma unroll 8
                for (int j = 0; j < 32; ++j) {
                    const int tl = tg0 + j;
                    gtw[(tl >> 2) * 256 + lane * 4 + (tl & 3)] =
                        src[tl * Vv + lab];
                }
                if (lane < 32) {
                    const int tl = tg0 + lane;
                    ((float*)(bk4 + (p & 1) * (CH / 4)))[tl] =
                        src[tl * Vv + (Vv - 1)];
                }
            }
        } else {
            // ---- consumer: 64 DP steps of chunk p-1 ------------------------
            const int c = p - 1;
            if (c >= 0) {
                __builtin_amdgcn_s_setprio(1);
                const float4* gbf = gt4 + (c & 1) * (CH / 4) * 64;
                const float4* bbf = bk4 + (c & 1) * (CH / 4);
                float4 gA = gbf[0 * 64 + lane], gB = gbf[1 * 64 + lane];
                float4 bA = bbf[0],             bB = bbf[1];
#pragma unroll
                for (int i = 0; i < 16; ++i) {
                    DO_STEP(gA.x + EPSF, bA.x + EPSF, false);
                    DO_STEP(gA.y + EPSF, bA.y + EPSF, false);
                    DO_STEP(gA.z + EPSF, bA.z + EPSF, false);
                    DO_STEP(gA.w + EPSF, bA.w + EPSF, (i & 3) == 3);
                    gA = gB; bA = bB;
                    if (i < 14) {
                        gB = gbf[(i + 2) * 64 + lane];
                        bB = bbf[i + 2];
                    }
                }
                __builtin_amdgcn_s_setprio(0);
            }
        }
        __syncthreads();
    }

    // ---- final combine (wave 0) -------------------------------------------
    if (wv == 0) {
        float vs = (lane < NSH) ? part[lane] : 0.0f;
        vs = wave_sum63(vs);
        if (lane == 63) {
            const float acc_ld  = vs;  // sum_t log2(S_t + V*eps)
            const float tot     = fmaxf(a128 + a_odd, 1e-37f);
            const float log2lik = __log2f(tot) + (float)eacc - acc_ld;
            const float ln_lik  = 0.69314718055994530942f * log2lik;
            const float loss    = -ln_lik;
            const float pp      = __expf(ln_lik);
            const float om      = 1.0f - pp;
            focal_ws[b] = 0.25f * om * om * loss;
        }
    }
}

// ---- focal mean -------------------------------------------------------------
__global__ void finalize_kernel(const float* __restrict__ focal_ws,
                                float* __restrict__ out) {
    const int i    = threadIdx.x;  // 256 threads = 4 waves
    const int lane = i & 63;
    const int wv   = i >> 6;

    float f = focal_ws[i];
#pragma unroll
    for (int off = 32; off > 0; off >>= 1) f += __shfl_xor(f, off);

    __shared__ float red[4];
    if (lane == 0) red[wv] = f;
    __syncthreads();
    if (i == 0)
        out[0] = (red[0] + red[1] + red[2] + red[3]) * (1.0f / (float)Bb);
}

extern "C" void kernel_launch(void* const* d_in, const int* in_sizes, int n_in,
                              void* d_out, int out_size, void* d_ws, size_t ws_size,
                              hipStream_t stream) {
    const int*   y_true = (const int*)d_in[0];    // [B, L] int32
    const float* y_pred = (const float*)d_in[1];  // [B, T, V] float32
    float* focal_ws = (float*)d_ws;               // [B]

    fused_kernel<<<Bb, 1024, 0, stream>>>(y_true, y_pred, focal_ws);
    finalize_kernel<<<1, 256, 0, stream>>>(focal_ws, (float*)d_out);
}